// Round 14
// baseline (350.568 us; speedup 1.0000x reference)
//
#include <hip/hip_runtime.h>
#include <stdint.h>

#define BB 8
#define CIN 256
#define NSP 16384      // H*W
#define HID 128

typedef __bf16 bfrag __attribute__((ext_vector_type(8)));
typedef float  f32x4 __attribute__((ext_vector_type(4)));
typedef unsigned short us8 __attribute__((ext_vector_type(8)));

__device__ __forceinline__ unsigned short f2bf(float f) {
  union { float f; unsigned int u; } v; v.f = f;
  unsigned int u = v.u;
  return (unsigned short)((u + 0x7FFFu + ((u >> 16) & 1u)) >> 16);  // RNE
}

// ---------------- prep: wkvb = bf16(w_qkv rows 128..383) ----------------
__global__ __launch_bounds__(256) void la_prep(const float* __restrict__ w_qkv,
                                               unsigned short* __restrict__ wkvb) {
  const int blk = blockIdx.x;
  const int t = threadIdx.x;
  const int off = (blk * 256 + t) * 4;   // 0..65532
  const float4 wv4 = *(const float4*)(w_qkv + (size_t)128 * CIN + off);
  ushort4 p;
  p.x = f2bf(wv4.x); p.y = f2bf(wv4.y); p.z = f2bf(wv4.z); p.w = f2bf(wv4.w);
  *(ushort4*)(wkvb + off) = p;
}

// ---------------- pass 1: k/v GEMM + exp + row-sum partials + context partials + xT writeback ----------------
// Round-12 structure (proven: no atomics, 128-n tile, 8 waves, 1 barrier/kc).
// NEW: each kc writes the already-transposed bf16 x tile back to xT[b][n][c]
// (1 ds_read_b128 + 1 coalesced 16B global store per thread per kc) so la_out
// can consume x as bf16 with zero LDS/conversion.
__global__ __launch_bounds__(512, 4) void la_fused(const float* __restrict__ x,
                                                   const unsigned short* __restrict__ wkvb,
                                                   unsigned short* __restrict__ xT,
                                                   float* __restrict__ ctxp,
                                                   float* __restrict__ sumsp) {
  __shared__ __align__(16) union {
    struct { unsigned short Xb[2][128][40]; } g;                              // 20480 B
    struct { unsigned short Lk[64][140]; unsigned short Lv[64][140];
             float Pc[4][1024]; } e;                                          // 52224 B
  } sh;
  const int chunk = blockIdx.x;
  const int n0 = chunk * 128;
  const int b = blockIdx.y;
  const int t = threadIdx.x;
  const int lane = t & 63, wv = t >> 6;
  const int l15 = lane & 15, q = lane >> 4;
  const int cl = t & 31;
  const int n16 = (t >> 5) * 8;
  const float* xp = x + (size_t)b * CIN * NSP + n0;
  unsigned short* xTb = xT + ((size_t)b * NSP + n0) * CIN;
  f32x4 acc[2][8];
#pragma unroll
  for (int i = 0; i < 2; ++i)
#pragma unroll
    for (int j = 0; j < 8; ++j) acc[i][j] = 0.0f;

  // prologue: load cols(kc=0), stage Xb[0], load cols(kc=1)
  float4 xa0, xa1;
  {
    const float* xr = xp + (size_t)cl * NSP + n16;
    xa0 = *(const float4*)xr;
    xa1 = *(const float4*)(xr + 4);
  }
  {
    sh.g.Xb[0][n16 + 0][cl] = f2bf(xa0.x);
    sh.g.Xb[0][n16 + 1][cl] = f2bf(xa0.y);
    sh.g.Xb[0][n16 + 2][cl] = f2bf(xa0.z);
    sh.g.Xb[0][n16 + 3][cl] = f2bf(xa0.w);
    sh.g.Xb[0][n16 + 4][cl] = f2bf(xa1.x);
    sh.g.Xb[0][n16 + 5][cl] = f2bf(xa1.y);
    sh.g.Xb[0][n16 + 6][cl] = f2bf(xa1.z);
    sh.g.Xb[0][n16 + 7][cl] = f2bf(xa1.w);
    const float* xr = xp + (size_t)(32 + cl) * NSP + n16;
    xa0 = *(const float4*)xr;
    xa1 = *(const float4*)(xr + 4);
  }
  __syncthreads();

#pragma unroll
  for (int kc = 0; kc < 8; ++kc) {
    const int p = kc & 1;
    // A-fragments: direct global loads from bf16 wkvb (L2-resident)
    bfrag a0 = *(const bfrag*)(wkvb + (size_t)(wv * 16 + l15) * CIN + kc * 32 + q * 8);
    bfrag a1 = *(const bfrag*)(wkvb + (size_t)(128 + wv * 16 + l15) * CIN + kc * 32 + q * 8);
    // stage next kc tile into the other buffer (regs loaded last iteration)
    if (kc < 7) {
      sh.g.Xb[p ^ 1][n16 + 0][cl] = f2bf(xa0.x);
      sh.g.Xb[p ^ 1][n16 + 1][cl] = f2bf(xa0.y);
      sh.g.Xb[p ^ 1][n16 + 2][cl] = f2bf(xa0.z);
      sh.g.Xb[p ^ 1][n16 + 3][cl] = f2bf(xa0.w);
      sh.g.Xb[p ^ 1][n16 + 4][cl] = f2bf(xa1.x);
      sh.g.Xb[p ^ 1][n16 + 5][cl] = f2bf(xa1.y);
      sh.g.Xb[p ^ 1][n16 + 6][cl] = f2bf(xa1.z);
      sh.g.Xb[p ^ 1][n16 + 7][cl] = f2bf(xa1.w);
      if (kc < 6) {
        const float* xr = xp + (size_t)((kc + 2) * 32 + cl) * NSP + n16;
        xa0 = *(const float4*)xr;
        xa1 = *(const float4*)(xr + 4);
      }
    }
    // xT writeback: 16B of the transposed bf16 tile per thread (coalesced)
    {
      const int rr = t >> 2, cc8 = (t & 3) * 8;
      const us8 wb = *(const us8*)&sh.g.Xb[p][rr][cc8];
      *(us8*)(xTb + (size_t)rr * CIN + kc * 32 + cc8) = wb;
    }
#pragma unroll
    for (int ni = 0; ni < 8; ++ni) {
      bfrag bbv = *(const bfrag*)&sh.g.Xb[p][ni * 16 + l15][q * 8];
      acc[0][ni] = __builtin_amdgcn_mfma_f32_16x16x32_bf16(a0, bbv, acc[0][ni], 0, 0, 0);
      acc[1][ni] = __builtin_amdgcn_mfma_f32_16x16x32_bf16(a1, bbv, acc[1][ni], 0, 0, 0);
    }
    __syncthreads();
  }

  // ---- exp in place on k accumulators ----
#pragma unroll
  for (int ni = 0; ni < 8; ++ni)
#pragma unroll
    for (int rg = 0; rg < 4; ++rg) acc[0][ni][rg] = __expf(acc[0][ni][rg]);

  // ---- k row-sum PARTIALS -> exclusive sumsp slot, NO atomics ----
  {
    float sp[4] = {0.f, 0.f, 0.f, 0.f};
#pragma unroll
    for (int ni = 0; ni < 8; ++ni)
#pragma unroll
      for (int rg = 0; rg < 4; ++rg) sp[rg] += acc[0][ni][rg];
#pragma unroll
    for (int rg = 0; rg < 4; ++rg) {
      float s = sp[rg];
      s += __shfl_down(s, 8, 16);
      s += __shfl_down(s, 4, 16);
      s += __shfl_down(s, 2, 16);
      s += __shfl_down(s, 1, 16);
      if (l15 == 0)
        sumsp[((size_t)b * 128 + chunk) * 128 + wv * 16 + q * 4 + rg] = s;
    }
  }
  // ---- context, two 64-row phases; combine quarters in LDS, exclusive ctxp store ----
  float* cp = ctxp + ((size_t)b * 128 + chunk) * 4096;
#pragma unroll
  for (int ph = 0; ph < 2; ++ph) {
    if ((wv >> 2) == ph) {
      const int r = (wv & 3) * 16 + q * 4;
#pragma unroll
      for (int ni = 0; ni < 8; ++ni)
#pragma unroll
        for (int rg = 0; rg < 4; ++rg) {
          sh.e.Lk[r + rg][ni * 16 + l15] = f2bf(acc[0][ni][rg]);   // already exp'd
          sh.e.Lv[r + rg][ni * 16 + l15] = f2bf(acc[1][ni][rg]);
        }
    }
    __syncthreads();
    const int hl = wv >> 2, nq = wv & 3;
    f32x4 c2[2][2];
    c2[0][0] = 0.f; c2[0][1] = 0.f; c2[1][0] = 0.f; c2[1][1] = 0.f;
    bfrag ka[2], vb[2];
#pragma unroll
    for (int d2 = 0; d2 < 2; ++d2)
      ka[d2] = *(const bfrag*)&sh.e.Lk[hl * 32 + d2 * 16 + l15][nq * 32 + q * 8];
#pragma unroll
    for (int e2 = 0; e2 < 2; ++e2)
      vb[e2] = *(const bfrag*)&sh.e.Lv[hl * 32 + e2 * 16 + l15][nq * 32 + q * 8];
#pragma unroll
    for (int d2 = 0; d2 < 2; ++d2)
#pragma unroll
      for (int e2 = 0; e2 < 2; ++e2)
        c2[d2][e2] = __builtin_amdgcn_mfma_f32_16x16x32_bf16(ka[d2], vb[e2], c2[d2][e2], 0, 0, 0);
    const int slot = hl * 2 + (nq & 1);
    if (nq < 2) {
#pragma unroll
      for (int d2 = 0; d2 < 2; ++d2)
#pragma unroll
        for (int e2 = 0; e2 < 2; ++e2)
#pragma unroll
          for (int rg = 0; rg < 4; ++rg)
            sh.e.Pc[slot][(d2 * 16 + q * 4 + rg) * 32 + e2 * 16 + l15] = c2[d2][e2][rg];
    }
    __syncthreads();
    if (nq >= 2) {
#pragma unroll
      for (int d2 = 0; d2 < 2; ++d2)
#pragma unroll
        for (int e2 = 0; e2 < 2; ++e2)
#pragma unroll
          for (int rg = 0; rg < 4; ++rg)
            sh.e.Pc[slot][(d2 * 16 + q * 4 + rg) * 32 + e2 * 16 + l15] += c2[d2][e2][rg];
    }
    __syncthreads();
    for (int idx = t; idx < 2048; idx += 512) {
      const int h2 = idx >> 10, pos = idx & 1023;
      cp[(ph * 2 + h2) * 1024 + pos] = sh.e.Pc[h2 * 2][pos] + sh.e.Pc[h2 * 2 + 1][pos];
    }
    __syncthreads();
  }
}

// ---------------- reduce: ctxp over 128 chunks -> ctxu; sumsp -> sums ----------------
__global__ __launch_bounds__(256) void la_reduce(const float* __restrict__ ctxp,
                                                 const float* __restrict__ sumsp,
                                                 float* __restrict__ ctxu,
                                                 float* __restrict__ sums) {
  const int blk = blockIdx.x;
  const int t = threadIdx.x;
  if (blk < 128) {
    const int gid = blk * 256 + t;            // 0..32767
    const int b = gid >> 12, pos = gid & 4095;
    const float* base = ctxp + (size_t)b * 128 * 4096 + pos;
    float s = 0.f;
#pragma unroll 8
    for (int c = 0; c < 128; ++c) s += base[(size_t)c * 4096];
    ctxu[gid] = s;
  } else {
    const int gid = (blk - 128) * 256 + t;    // 0..1023
    const int b = gid >> 7, row = gid & 127;
    const float* base = sumsp + (size_t)b * 128 * 128 + row;
    float s = 0.f;
#pragma unroll 8
    for (int c = 0; c < 128; ++c) s += base[c * 128];
    sums[gid] = s;
  }
}

// ---------------- mid: weff row (in LDS) -> wcomb row, fused (unchanged) ----------------
__global__ __launch_bounds__(256) void la_mid(const float* __restrict__ w_out,
                                              const float* __restrict__ ctxu,
                                              const float* __restrict__ sums,
                                              const float* __restrict__ w_qkv,
                                              unsigned short* __restrict__ wcomb) {
  __shared__ float wrow[128];
  const int o = blockIdx.x;
  const int b = blockIdx.y;
  const int t = threadIdx.x;
  if (t < 128) {
    const int h = t >> 5, d = t & 31;
    const float* wr = w_out + (size_t)o * HID + h * 32;
    const float* cr = ctxu + ((size_t)(b * 4 + h) * 32 + d) * 32;
    float s = 0.f;
#pragma unroll 8
    for (int e = 0; e < 32; ++e) s += wr[e] * cr[e];
    wrow[t] = s * (1.0f / sums[b * 128 + t]);
  }
  __syncthreads();
  float s = 0.f;
#pragma unroll 8
  for (int hd = 0; hd < 128; ++hd) s += wrow[hd] * w_qkv[(size_t)hd * CIN + t];
  wcomb[((size_t)b * 256 + o) * 256 + t] = f2bf(s);
}

// ---------------- out[b][o][n] = sum_c Wcomb[b][o][c] * xT[n][c] + b_out[o] ----------------
// NO LDS, NO BARRIERS: A-frags from wcomb (bf16, L2) and B-frags from xT (bf16, L3)
// are both direct contiguous 16B global loads in exact MFMA fragment layout.
// Waves free-run; latency hidden by TLP + compiler pipelining across kc.
__global__ __launch_bounds__(512, 4) void la_out(const unsigned short* __restrict__ wcomb,
                                                 const unsigned short* __restrict__ xT,
                                                 const float* __restrict__ b_out,
                                                 float* __restrict__ out) {
  const int n0 = blockIdx.x * 128;
  const int b = blockIdx.y;
  const int t = threadIdx.x;
  const int lane = t & 63, wv = t >> 6;
  const int l15 = lane & 15, q = lane >> 4;
  const int wm = (wv & 3) * 64;
  const int wn = (wv >> 2) * 64;
  const unsigned short* abase = wcomb + (size_t)b * 256 * 256;
  const unsigned short* xb = xT + ((size_t)b * NSP + n0) * CIN;
  f32x4 acc[4][4];
#pragma unroll
  for (int i = 0; i < 4; ++i)
#pragma unroll
    for (int j = 0; j < 4; ++j) acc[i][j] = 0.0f;

#pragma unroll
  for (int kc = 0; kc < 8; ++kc) {
    bfrag a[4], bv[4];
#pragma unroll
    for (int mi = 0; mi < 4; ++mi)
      a[mi] = *(const bfrag*)(abase + (size_t)(wm + mi * 16 + l15) * 256 + kc * 32 + q * 8);
#pragma unroll
    for (int ni = 0; ni < 4; ++ni)
      bv[ni] = *(const bfrag*)(xb + (size_t)(wn + ni * 16 + l15) * CIN + kc * 32 + q * 8);
#pragma unroll
    for (int ni = 0; ni < 4; ++ni)
#pragma unroll
      for (int mi = 0; mi < 4; ++mi)
        acc[mi][ni] = __builtin_amdgcn_mfma_f32_16x16x32_bf16(a[mi], bv[ni], acc[mi][ni], 0, 0, 0);
  }
  float* obase = out + (size_t)b * 256 * NSP;
#pragma unroll
  for (int mi = 0; mi < 4; ++mi) {
    const int ob = wm + mi * 16 + q * 4;
    const float4 bias = *(const float4*)(b_out + ob);
    float ba[4] = {bias.x, bias.y, bias.z, bias.w};
#pragma unroll
    for (int ni = 0; ni < 4; ++ni) {
      const int n = n0 + wn + ni * 16 + l15;
#pragma unroll
      for (int rg = 0; rg < 4; ++rg)
        obase[(size_t)(ob + rg) * NSP + n] = acc[mi][ni][rg] + ba[rg];
    }
  }
}

// ---------------- workspace layout ----------------
// wkvb  : 0        , 131072 B    (256x256 bf16 k/v weights)
// xT    : 131072   , 67108864 B  (bf16 [b][n][c], written by la_fused)
// ctxp  : 67239936 , 16777216 B  (fp32 [b][chunk][4096])
// sumsp : 84017152 , 524288 B    (fp32 [b][chunk][128])
// ctxu  : 84541440 , 131072 B
// sums  : 84672512 , 4096 B
// wcomb : 84676608 , 1048576 B   (bf16)
// total ~85.7 MB

extern "C" void kernel_launch(void* const* d_in, const int* in_sizes, int n_in,
                              void* d_out, int out_size, void* d_ws, size_t ws_size,
                              hipStream_t stream) {
  (void)in_sizes; (void)n_in; (void)out_size; (void)ws_size;
  const float* x     = (const float*)d_in[0];
  const float* w_qkv = (const float*)d_in[1];
  const float* w_out = (const float*)d_in[2];
  const float* b_out = (const float*)d_in[3];
  float* out = (float*)d_out;
  char* ws = (char*)d_ws;
  unsigned short* wkvb  = (unsigned short*)(ws);
  unsigned short* xTws  = (unsigned short*)(ws + 131072);
  float* ctxp           = (float*)(ws + 67239936);
  float* sumsp          = (float*)(ws + 84017152);
  float* ctxu           = (float*)(ws + 84541440);
  float* sums           = (float*)(ws + 84672512);
  unsigned short* wcomb = (unsigned short*)(ws + 84676608);

  la_prep<<<dim3(64), dim3(256), 0, stream>>>(w_qkv, wkvb);
  la_fused<<<dim3(NSP / 128, BB), dim3(512), 0, stream>>>(x, wkvb, xTws, ctxp, sumsp);
  la_reduce<<<dim3(132), dim3(256), 0, stream>>>(ctxp, sumsp, ctxu, sums);
  la_mid<<<dim3(256, BB), dim3(256), 0, stream>>>(w_out, ctxu, sums, w_qkv, wcomb);
  la_out<<<dim3(NSP / 128, BB), dim3(512), 0, stream>>>(wcomb, xTws, b_out, out);
}